// Round 8
// baseline (47642.908 us; speedup 1.0000x reference)
//
#include <hip/hip_runtime.h>
#include <hip/hip_bf16.h>
#include <cstdint>
#include <cstddef>

#define T_DIM 512
#define B_DIM 256
#define D_DIM 256
#define H_DIM 512
#define O_DIM 256
#define NSTEP 10
#define WIN 16

// ---- workspace layout ----
#define WS_WHHT 0u
#define WS_WIHT (1u << 20)
#define WS_WOUT ((1u << 20) + (512u << 10))
#define WS_PSUM (2u << 20)
#define WS_XCW  ((2u << 20) + (512u << 10))   // 8 MB  [256][16][512]
#define WS_PART (WS_XCW + (8u << 20))         // 4 MB  [32][8][8][512]
#define WS_SG   (WS_PART + (4u << 20))        // 512 K [256][512]
#define WS_CTRL (WS_SG + (512u << 10))        // 4 K   [32][32] uints
#define WS_NEED (WS_CTRL + 4096u)

#define AGL(p) __hip_atomic_load((p), __ATOMIC_RELAXED, __HIP_MEMORY_SCOPE_AGENT)
#define AGS(p, v) __hip_atomic_store((p), (v), __ATOMIC_RELAXED, __HIP_MEMORY_SCOPE_AGENT)

__device__ __forceinline__ unsigned short f2bf(float f) {
    __hip_bfloat16 b = __float2bfloat16(f);   // RNE
    return *reinterpret_cast<unsigned short*>(&b);
}

// ---------------- transposes (tiny) ----------------
__global__ void k_transpose(const float* __restrict__ W_hh,
                            const float* __restrict__ W_ih,
                            const float* __restrict__ W_out,
                            float* __restrict__ whhT,   // [512][512] k-major
                            float* __restrict__ wihT,   // [256][512] d-major
                            float* __restrict__ woutT)  // [512][256] h-major
{
    int idx = blockIdx.x * blockDim.x + threadIdx.x;
    if (idx < 512 * 512) {
        int k = idx >> 9, h = idx & 511;
        whhT[k * 512 + h] = W_hh[h * 512 + k];
    } else if (idx < 512 * 512 + 256 * 512) {
        int j = idx - 512 * 512;
        int d = j >> 9, h = j & 511;
        wihT[d * 512 + h] = W_ih[h * 257 + d];   // W_ih row length = 257
    } else if (idx < 512 * 512 + 256 * 512 + 512 * 256) {
        int j = idx - (512 * 512 + 256 * 512);
        int h = j >> 8, o = j & 255;
        woutT[h * 256 + o] = W_out[o * 512 + h];
    }
}

// ---------------- cooperative ACT recurrence: 8-CU k-split groups ----------
// 256 blocks x 1024 threads, ~152 KB LDS -> exactly 1 block/CU, all resident.
// Group g = 8 CUs (XCD-local under round-robin bid%8); CU c holds W k-slice
// [c*64,(c+1)*64) in LDS (128 KB). Phase A: all CUs compute k-slice partials
// for all 8 rows of the group (zero global W traffic). Phase B: CU c owns row
// 8g+c: sums 8 partials (agent-scope mailbox), tanh, halt butterfly, halting
// scalars, publishes s_next. Two group barriers/pass (fence+atomic+spin).
// Owner-local xc window refill (r7-token-identical GEMM) every 16 t.
__global__ __launch_bounds__(1024, 1) void k_recur8(
    const float* __restrict__ x,      // [T,B,256]
    const float* __restrict__ wihT,   // [256][512]
    const float* __restrict__ whhT,   // [512][512] k-major
    const float* __restrict__ W_ih,   // flag col at [h*257+256]
    const float* __restrict__ w_halt,
    const float* __restrict__ b_ih,
    const float* __restrict__ b_hh,
    const float* __restrict__ b_halt,
    float* out,                       // d_out (y region reused as bf16 s_acc)
    float* __restrict__ psum_g,       // [T*B]
    float* __restrict__ xcw_g,        // [256][16][512]
    float* __restrict__ part_g,       // [32][8 writer][8 row][512]
    float* __restrict__ s_g,          // [256][512]  (memset 0 per launch)
    unsigned* __restrict__ ctrl)      // [32][32]    (memset 0 per launch)
{
    __shared__ __align__(16) float w_l[64 * 512];    // 128 KB k-major slice
    __shared__ __align__(16) float s_l[8 * 64];      // [row][k] slice
    __shared__ __align__(16) float xst[WIN * D_DIM]; // 16 KB refill staging
    __shared__ float whalt_l[512];
    __shared__ float flag_l[512];
    __shared__ float bias_l[512];
    __shared__ float red[8];
    __shared__ unsigned exit_l;

    const int tid = threadIdx.x;
    const int h = tid & 511;
    const int kh = tid >> 9;
    const int kh4 = kh * 4;
    const int wave = tid >> 6;
    const int lane = tid & 63;

    const int bid = blockIdx.x;
    const int slot = bid >> 3;
    const int c = slot & 7;                  // CU index in group
    const int g = (bid & 7) * 4 + (slot >> 3);  // group 0..31 (XCD-local)
    const int g8 = g * 8;
    const int ro = g8 + c;                   // owned batch row

    // stage W slice (straight copy of whhT rows [c*64, c*64+64))
    {
        const float4* wsrc = (const float4*)(whhT + (size_t)c * 64 * 512);
        float4* wdst = (float4*)w_l;
        for (int i = tid; i < 64 * 512 / 4; i += 1024) wdst[i] = wsrc[i];
    }
    if (tid < 512) {
        whalt_l[tid] = w_halt[tid];
        flag_l[tid] = W_ih[tid * 257 + 256];
        bias_l[tid] = b_ih[tid] + b_hh[tid];
    }
    __syncthreads();

    const float bh = b_halt[0];
    const float THR = 1.0f - 0.01f;
    unsigned short* sacc_out = (unsigned short*)out;
    float* rho_out = out + (size_t)T_DIM * B_DIM * O_DIM;
    float* n_out = rho_out + (size_t)T_DIM * B_DIM;

    unsigned* cnt = &ctrl[g * 32];
    unsigned* done = &ctrl[g * 32 + 16];
    unsigned bar_target = 0;

    // replicated row state (uniform across the block)
    int t = 0, nstep = 0, active = 1;
    float hsum = 0.f, runf = 1.f, stepsf = 0.f, remf = 0.f, ps = 0.f;
    float sacc_v = 0.f;   // meaningful on kh==0 threads (indexed by h)

    for (;;) {
        // ---------------- phase A: k-slice matvec for all 8 rows ----------
        if (tid < 512)
            s_l[tid] = AGL(&s_g[(size_t)(g8 + (tid >> 6)) * 512 + c * 64 + (tid & 63)]);
        __syncthreads();

        {
            float4 A0{0.f, 0.f, 0.f, 0.f}, A1 = A0, A2 = A0, A3 = A0;
#pragma unroll
            for (int q = 0; q < 16; ++q) {
                const float w0 = w_l[(4 * q + 0) * 512 + h];
                const float w1 = w_l[(4 * q + 1) * 512 + h];
                const float w2 = w_l[(4 * q + 2) * 512 + h];
                const float w3 = w_l[(4 * q + 3) * 512 + h];
                const float4 s0 = *(const float4*)&s_l[(kh4 + 0) * 64 + 4 * q];
                const float4 s1 = *(const float4*)&s_l[(kh4 + 1) * 64 + 4 * q];
                const float4 s2 = *(const float4*)&s_l[(kh4 + 2) * 64 + 4 * q];
                const float4 s3 = *(const float4*)&s_l[(kh4 + 3) * 64 + 4 * q];
                A0.x += s0.x * w0; A0.y += s0.y * w1; A0.z += s0.z * w2; A0.w += s0.w * w3;
                A1.x += s1.x * w0; A1.y += s1.y * w1; A1.z += s1.z * w2; A1.w += s1.w * w3;
                A2.x += s2.x * w0; A2.y += s2.y * w1; A2.z += s2.z * w2; A2.w += s2.w * w3;
                A3.x += s3.x * w0; A3.y += s3.y * w1; A3.z += s3.z * w2; A3.w += s3.w * w3;
            }
            const float pd0 = (A0.x + A0.y) + (A0.z + A0.w);
            const float pd1 = (A1.x + A1.y) + (A1.z + A1.w);
            const float pd2 = (A2.x + A2.y) + (A2.z + A2.w);
            const float pd3 = (A3.x + A3.y) + (A3.z + A3.w);
            const size_t pb = ((size_t)(g8 + c) * 8 + kh4) * 512 + h;
            AGS(&part_g[pb], pd0);
            AGS(&part_g[pb + 512], pd1);
            AGS(&part_g[pb + 1024], pd2);
            AGS(&part_g[pb + 1536], pd3);
        }

        // ---- group barrier A ----
        __syncthreads();
        bar_target += 8;
        if (tid == 0) {
            __threadfence();
            __hip_atomic_fetch_add(cnt, 1u, __ATOMIC_RELAXED, __HIP_MEMORY_SCOPE_AGENT);
            while (AGL(cnt) < bar_target) __builtin_amdgcn_s_sleep(1);
            __threadfence();
        }
        __syncthreads();

        // ---------------- phase B: owner processes its row ----------------
        if (active) {
            if (nstep == 0 && (t & (WIN - 1)) == 0) {
                // refill xc window [t, t+16) for row ro (r7-token-identical)
                for (int i = tid; i < WIN * D_DIM; i += 1024)
                    xst[i] = x[(size_t)(t + (i >> 8)) * (B_DIM * D_DIM) +
                               (size_t)ro * D_DIM + (i & 255)];
                __syncthreads();
                float xa[8];
#pragma unroll
                for (int jj = 0; jj < 8; ++jj) xa[jj] = 0.f;
                for (int d = 0; d < 256; d += 4) {
                    const float u0 = wihT[(d + 0) * 512 + h];
                    const float u1 = wihT[(d + 1) * 512 + h];
                    const float u2 = wihT[(d + 2) * 512 + h];
                    const float u3 = wihT[(d + 3) * 512 + h];
#pragma unroll
                    for (int jj = 0; jj < 8; ++jj) {
                        const float4 xv = *(const float4*)&xst[(kh * 8 + jj) * 256 + d];
                        xa[jj] += xv.x * u0;
                        xa[jj] += xv.y * u1;
                        xa[jj] += xv.z * u2;
                        xa[jj] += xv.w * u3;
                    }
                }
#pragma unroll
                for (int jj = 0; jj < 8; ++jj)
                    xcw_g[((size_t)ro * WIN + kh * 8 + jj) * 512 + h] =
                        xa[jj] + bias_l[h];
                __syncthreads();
            }

            float sn = 0.f;
            if (kh == 0) {
                float pp[8];
#pragma unroll
                for (int cw = 0; cw < 8; ++cw)
                    pp[cw] = AGL(&part_g[((size_t)(g8 + cw) * 8 + c) * 512 + h]);
                const float pd8 = ((pp[0] + pp[1]) + (pp[2] + pp[3])) +
                                  ((pp[4] + pp[5]) + (pp[6] + pp[7]));
                float base = xcw_g[((size_t)ro * WIN + (t & (WIN - 1))) * 512 + h];
                if (nstep == 0) base += flag_l[h];
                const float pre = base + pd8;
                sn = tanhf(pre);
                float pt = sn * whalt_l[h];
#pragma unroll
                for (int m = 1; m < 64; m <<= 1) pt += __shfl_xor(pt, m, 64);
                if (lane == 0) red[wave] = pt;
            }
            __syncthreads();

            const float dotv = ((red[0] + red[1]) + (red[2] + red[3])) +
                               ((red[4] + red[5]) + (red[6] + red[7]));
            const float z = dotv + bh;
            const float hn = 1.f / (1.f + expf(-z));
            const float ns = hsum + hn;
            const float stop = (ns >= THR) ? runf : 0.f;
            const float still = runf - stop;
            const float rem = (1.f - hsum) * stop;
            const float p = hn * still + rem;
            ps += p;
            stepsf += runf;   // old running, matches reference order
            remf += rem;
            hsum = ns;
            runf = still;
            nstep += 1;
            const int adv = (still == 0.f) || (nstep == NSTEP);
            if (kh == 0) {
                sacc_v += p * sn;
                const float sval = adv ? sacc_v : sn;
                AGS(&s_g[(size_t)ro * 512 + h], sval);
                if (adv)
                    sacc_out[((size_t)t * B_DIM + ro) * 512 + h] = f2bf(sacc_v);
            }
            if (adv) {
                if (tid == 0) {
                    const int bi = t * B_DIM + ro;
                    psum_g[bi] = ps;
                    rho_out[bi] = stepsf + remf;
                    n_out[bi] = stepsf;
                }
                hsum = 0.f; runf = 1.f; stepsf = 0.f; remf = 0.f; ps = 0.f;
                nstep = 0; sacc_v = 0.f;
                t += 1;
                if (t == T_DIM) {
                    active = 0;
                    if (tid == 0)
                        __hip_atomic_fetch_add(done, 1u, __ATOMIC_RELAXED,
                                               __HIP_MEMORY_SCOPE_AGENT);
                }
            }
        }

        // ---- group barrier B + exit check ----
        __syncthreads();
        bar_target += 8;
        if (tid == 0) {
            __threadfence();
            __hip_atomic_fetch_add(cnt, 1u, __ATOMIC_RELAXED, __HIP_MEMORY_SCOPE_AGENT);
            while (AGL(cnt) < bar_target) __builtin_amdgcn_s_sleep(1);
            __threadfence();
            exit_l = AGL(done);
        }
        __syncthreads();
        if (exit_l == 8u) break;
    }
}

// ---------------- fallback: r7 streaming kernel (unchanged, proven) --------
__global__ __launch_bounds__(1024, 1) void k_recur7(
    const float* __restrict__ x, const float* __restrict__ wihT,
    const float* __restrict__ whhT, const float* __restrict__ W_ih,
    const float* __restrict__ w_halt, const float* __restrict__ b_ih,
    const float* __restrict__ b_hh, const float* __restrict__ b_halt,
    float* out, float* __restrict__ psum_g)
{
    __shared__ __align__(16) float sb[2][2][H_DIM];
    __shared__ __align__(16) float xcw[2][WIN][H_DIM];
    __shared__ float prt[2][2][H_DIM];
    __shared__ __align__(16) float xst[WIN * D_DIM];
    __shared__ float whalt_l[H_DIM];
    __shared__ float flag_l[H_DIM];
    __shared__ float bias_l[H_DIM];
    __shared__ float red[16];

    const int tid = threadIdx.x;
    const int h = tid & 511;
    const int kh = tid >> 9;
    const int b0 = blockIdx.x * 2;
    const int wave = tid >> 6;
    const int lane = tid & 63;

    if (!kh) {
        whalt_l[h] = w_halt[h];
        flag_l[h] = W_ih[h * 257 + 256];
        bias_l[h] = b_ih[h] + b_hh[h];
    }
    sb[kh][0][h] = 0.f;

    const float bh = b_halt[0];
    const float THR = 1.0f - 0.01f;
    unsigned short* sacc_out = (unsigned short*)out;
    float* rho_out = out + (size_t)T_DIM * B_DIM * O_DIM;
    float* n_out = rho_out + (size_t)T_DIM * B_DIM;
    const float* wc = whhT + (size_t)kh * 256 * 512 + h;

    int t0 = 0, t1 = 0, nst0 = 0, nst1 = 0, cur0 = 0, cur1 = 0;
    int act0 = 1, act1 = 1;
    float hsum0 = 0.f, runf0 = 1.f, steps0 = 0.f, rem0 = 0.f, ps0 = 0.f;
    float hsum1 = 0.f, runf1 = 1.f, steps1 = 0.f, rem1 = 0.f, ps1 = 0.f;
    float sacc_v = 0.f;
    int refill0 = 1, refill1 = 1;

#define DO_REFILL(RROW, TB, BR)                                               \
    {                                                                         \
        __syncthreads();                                                      \
        for (int i = tid; i < WIN * D_DIM; i += 1024)                         \
            xst[i] = x[((size_t)((TB) + (i >> 8)) * B_DIM + (BR)) * D_DIM +   \
                       (i & 255)];                                            \
        __syncthreads();                                                      \
        float xa[8];                                                          \
        _Pragma("unroll") for (int jj = 0; jj < 8; ++jj) xa[jj] = 0.f;        \
        for (int d = 0; d < 256; d += 4) {                                    \
            const float u0 = wihT[(d + 0) * 512 + h];                         \
            const float u1 = wihT[(d + 1) * 512 + h];                         \
            const float u2 = wihT[(d + 2) * 512 + h];                         \
            const float u3 = wihT[(d + 3) * 512 + h];                         \
            _Pragma("unroll") for (int jj = 0; jj < 8; ++jj) {                \
                const float4 xv =                                             \
                    *(const float4*)&xst[(kh * 8 + jj) * 256 + d];            \
                xa[jj] += xv.x * u0;                                          \
                xa[jj] += xv.y * u1;                                          \
                xa[jj] += xv.z * u2;                                          \
                xa[jj] += xv.w * u3;                                          \
            }                                                                 \
        }                                                                     \
        _Pragma("unroll") for (int jj = 0; jj < 8; ++jj)                      \
            xcw[RROW][kh * 8 + jj][h] = xa[jj] + bias_l[h];                   \
        __syncthreads();                                                      \
    }

    DO_REFILL(0, 0, b0)
    DO_REFILL(1, 0, b0 + 1)

    while (act0 || act1) {
        const float* s0p = &sb[0][cur0][kh << 8];
        const float* s1p = &sb[1][cur1][kh << 8];
        float4 A0[4], A1[4];
#pragma unroll
        for (int cc = 0; cc < 4; ++cc) {
            A0[cc] = float4{0.f, 0.f, 0.f, 0.f};
            A1[cc] = float4{0.f, 0.f, 0.f, 0.f};
        }
#pragma unroll 4
        for (int i = 0; i < 16; ++i) {
#pragma unroll
            for (int cc = 0; cc < 4; ++cc) {
                const int kbase = i * 16 + cc * 4;
                const float4 sv0 = *(const float4*)&s0p[kbase];
                const float4 sv1 = *(const float4*)&s1p[kbase];
                const float w0 = wc[(size_t)(kbase + 0) * 512];
                const float w1 = wc[(size_t)(kbase + 1) * 512];
                const float w2 = wc[(size_t)(kbase + 2) * 512];
                const float w3 = wc[(size_t)(kbase + 3) * 512];
                A0[cc].x += sv0.x * w0; A0[cc].y += sv0.y * w1;
                A0[cc].z += sv0.z * w2; A0[cc].w += sv0.w * w3;
                A1[cc].x += sv1.x * w0; A1[cc].y += sv1.y * w1;
                A1[cc].z += sv1.z * w2; A1[cc].w += sv1.w * w3;
            }
        }
        {
            const float g0 = (A0[0].x + A0[0].y) + (A0[0].z + A0[0].w);
            const float g1 = (A0[1].x + A0[1].y) + (A0[1].z + A0[1].w);
            const float g2 = (A0[2].x + A0[2].y) + (A0[2].z + A0[2].w);
            const float g3 = (A0[3].x + A0[3].y) + (A0[3].z + A0[3].w);
            prt[kh][0][h] = (g0 + g1) + (g2 + g3);
        }
        {
            const float g0 = (A1[0].x + A1[0].y) + (A1[0].z + A1[0].w);
            const float g1 = (A1[1].x + A1[1].y) + (A1[1].z + A1[1].w);
            const float g2 = (A1[2].x + A1[2].y) + (A1[2].z + A1[2].w);
            const float g3 = (A1[3].x + A1[3].y) + (A1[3].z + A1[3].w);
            prt[kh][1][h] = (g0 + g1) + (g2 + g3);
        }
        __syncthreads();

        const int myact = kh ? act1 : act0;
        const int mynst = kh ? nst1 : nst0;
        const int mytw = (kh ? t1 : t0) & (WIN - 1);
        float sn = 0.f;
        if (myact) {
            float base = xcw[kh][mytw][h];
            if (mynst == 0) base += flag_l[h];
            const float pre = (base + prt[0][kh][h]) + prt[1][kh][h];
            sn = tanhf(pre);
            sb[kh][(kh ? cur1 : cur0) ^ 1][h] = sn;
            float pt = sn * whalt_l[h];
#pragma unroll
            for (int m = 1; m < 64; m <<= 1) pt += __shfl_xor(pt, m, 64);
            if (lane == 0) red[wave] = pt;
        }
        __syncthreads();

        int adv0 = 0, adv1 = 0;
        float p_mine = 0.f;
        if (act0) {
            const float dotv = ((red[0] + red[1]) + (red[2] + red[3])) +
                               ((red[4] + red[5]) + (red[6] + red[7]));
            const float z = dotv + bh;
            const float hn = 1.f / (1.f + expf(-z));
            const float ns = hsum0 + hn;
            const float stop = (ns >= THR) ? runf0 : 0.f;
            const float still = runf0 - stop;
            const float rem = (1.f - hsum0) * stop;
            const float p = hn * still + rem;
            if (kh == 0) p_mine = p;
            ps0 += p; steps0 += runf0; rem0 += rem;
            hsum0 = ns; runf0 = still; cur0 ^= 1; nst0 += 1;
            adv0 = (still == 0.f) || (nst0 == NSTEP);
        }
        if (act1) {
            const float dotv = ((red[8] + red[9]) + (red[10] + red[11])) +
                               ((red[12] + red[13]) + (red[14] + red[15]));
            const float z = dotv + bh;
            const float hn = 1.f / (1.f + expf(-z));
            const float ns = hsum1 + hn;
            const float stop = (ns >= THR) ? runf1 : 0.f;
            const float still = runf1 - stop;
            const float rem = (1.f - hsum1) * stop;
            const float p = hn * still + rem;
            if (kh == 1) p_mine = p;
            ps1 += p; steps1 += runf1; rem1 += rem;
            hsum1 = ns; runf1 = still; cur1 ^= 1; nst1 += 1;
            adv1 = (still == 0.f) || (nst1 == NSTEP);
        }
        if (myact) sacc_v += p_mine * sn;

        const int myadv = kh ? adv1 : adv0;
        if (myadv) {
            const int myt = kh ? t1 : t0;
            sb[kh][kh ? cur1 : cur0][h] = sacc_v;
            sacc_out[((size_t)myt * B_DIM + b0 + kh) * (size_t)H_DIM + h] =
                f2bf(sacc_v);
            if (h == 0) {
                const int bi = myt * B_DIM + b0 + kh;
                psum_g[bi] = kh ? ps1 : ps0;
                rho_out[bi] = (kh ? steps1 + rem1 : steps0 + rem0);
                n_out[bi] = kh ? steps1 : steps0;
            }
            sacc_v = 0.f;
        }
        if (adv0) {
            hsum0 = 0.f; runf0 = 1.f; steps0 = 0.f; rem0 = 0.f; ps0 = 0.f;
            nst0 = 0; t0 += 1;
            if (t0 == T_DIM) act0 = 0;
            else if ((t0 & (WIN - 1)) == 0) refill0 = 1;
        }
        if (adv1) {
            hsum1 = 0.f; runf1 = 1.f; steps1 = 0.f; rem1 = 0.f; ps1 = 0.f;
            nst1 = 0; t1 += 1;
            if (t1 == T_DIM) act1 = 0;
            else if ((t1 & (WIN - 1)) == 0) refill1 = 1;
        }
        __syncthreads();

        if (refill0 && act0) DO_REFILL(0, t0, b0)
        if (refill1 && act1) DO_REFILL(1, t1, b0 + 1)
        refill0 = 0;
        refill1 = 0;
    }
#undef DO_REFILL
}

// ---------------- y = s_acc @ W_out.T + psum * b_out ----------------
__global__ __launch_bounds__(256) void k_y(
    const float* __restrict__ woutT,  // [512][256]
    const float* __restrict__ b_out,
    const float* __restrict__ psum_g,
    float* out)
{
    __shared__ float sl[16][512];
    __shared__ float pl[16];
    const int tid = threadIdx.x;
    const int tb0 = blockIdx.x * 16;
    const unsigned short* sacc = (const unsigned short*)out;
    for (int i = tid; i < 16 * 512; i += 256) {
        unsigned int u = sacc[(size_t)tb0 * 512 + i];
        u <<= 16;
        sl[i >> 9][i & 511] = __uint_as_float(u);
    }
    if (tid < 16) pl[tid] = psum_g[tb0 + tid];
    __syncthreads();
    const int o = tid;
    float acc[16];
#pragma unroll
    for (int r = 0; r < 16; ++r) acc[r] = 0.f;
    for (int hh = 0; hh < 512; hh += 4) {
        const float wv0 = woutT[(hh + 0) * 256 + o];
        const float wv1 = woutT[(hh + 1) * 256 + o];
        const float wv2 = woutT[(hh + 2) * 256 + o];
        const float wv3 = woutT[(hh + 3) * 256 + o];
#pragma unroll
        for (int r = 0; r < 16; ++r) {
            const float4 sv = *(const float4*)&sl[r][hh];
            acc[r] += sv.x * wv0;
            acc[r] += sv.y * wv1;
            acc[r] += sv.z * wv2;
            acc[r] += sv.w * wv3;
        }
    }
    const float bo = b_out[o];
    for (int r = 0; r < 16; ++r)
        out[(size_t)(tb0 + r) * 256 + o] = acc[r] + pl[r] * bo;
}

extern "C" void kernel_launch(void* const* d_in, const int* in_sizes, int n_in,
                              void* d_out, int out_size, void* d_ws, size_t ws_size,
                              hipStream_t stream) {
    const float* x = (const float*)d_in[0];
    const float* W_ih = (const float*)d_in[1];
    const float* b_ih = (const float*)d_in[2];
    const float* W_hh = (const float*)d_in[3];
    const float* b_hh = (const float*)d_in[4];
    const float* W_halt = (const float*)d_in[5];
    const float* b_halt = (const float*)d_in[6];
    const float* W_out = (const float*)d_in[7];
    const float* b_out = (const float*)d_in[8];
    float* out = (float*)d_out;

    char* ws = (char*)d_ws;
    float* whhT = (float*)(ws + WS_WHHT);
    float* wihT = (float*)(ws + WS_WIHT);
    float* woutT = (float*)(ws + WS_WOUT);
    float* psum = (float*)(ws + WS_PSUM);
    float* xcw = (float*)(ws + WS_XCW);
    float* part = (float*)(ws + WS_PART);
    float* s_g = (float*)(ws + WS_SG);
    unsigned* ctrl = (unsigned*)(ws + WS_CTRL);

    const bool coop = (ws_size >= (size_t)WS_NEED);

    hipLaunchKernelGGL(k_transpose, dim3(2048), dim3(256), 0, stream,
                       W_hh, W_ih, W_out, whhT, wihT, woutT);
    if (coop) {
        hipMemsetAsync(ws + WS_SG, 0, (512u << 10) + 4096u, stream);
        hipLaunchKernelGGL(k_recur8, dim3(256), dim3(1024), 0, stream,
                           x, wihT, whhT, W_ih, W_halt, b_ih, b_hh, b_halt,
                           out, psum, xcw, part, s_g, ctrl);
    } else {
        hipLaunchKernelGGL(k_recur7, dim3(B_DIM / 2), dim3(1024), 0, stream,
                           x, wihT, whhT, W_ih, W_halt, b_ih, b_hh, b_halt,
                           out, psum);
    }
    hipLaunchKernelGGL(k_y, dim3((T_DIM * B_DIM) / 16), dim3(256), 0, stream,
                       woutT, b_out, psum, out);
}

// Round 10
// 31582.892 us; speedup vs baseline: 1.5085x; 1.5085x over previous
//
#include <hip/hip_runtime.h>
#include <hip/hip_bf16.h>
#include <cstdint>
#include <cstddef>

#define T_DIM 512
#define B_DIM 256
#define D_DIM 256
#define H_DIM 512
#define O_DIM 256
#define NSTEP 10
#define WIN 16

__device__ __forceinline__ unsigned short f2bf(float f) {
    __hip_bfloat16 b = __float2bfloat16(f);   // RNE
    return *reinterpret_cast<unsigned short*>(&b);
}

// ---------------- prep: W packing + transposes ----------------
// whh4 float4-unit layout: unit q, column h at ((float4*)whh4)[q*512+h]
//   = float4{ W_hh[h][4q], W_hh[h][4q+1], W_hh[h][4q+2], W_hh[h][4q+3] }
// -> a thread streaming column h reads consecutive-lane-coalesced dwordx4.
__global__ void k_prep(const float* __restrict__ W_hh,
                       const float* __restrict__ W_ih,
                       const float* __restrict__ W_out,
                       float* __restrict__ whh4,   // [128][512] float4 units
                       float* __restrict__ wihT,   // [256][512] d-major
                       float* __restrict__ woutT)  // [512][256] h-major
{
    int idx = blockIdx.x * blockDim.x + threadIdx.x;
    if (idx < 65536) {
        int q = idx >> 9, h = idx & 511;
        ((float4*)whh4)[q * 512 + h] = ((const float4*)W_hh)[h * 128 + q];
    } else if (idx < 65536 + 131072) {
        int j = idx - 65536;
        int d = j >> 9, h = j & 511;
        wihT[d * 512 + h] = W_ih[h * 257 + d];   // W_ih row length = 257
    } else if (idx < 65536 + 131072 + 131072) {
        int j = idx - (65536 + 131072);
        int h = j >> 8, o = j & 255;
        woutT[h * 256 + o] = W_out[o * 512 + h];
    }
}

// ---------------- sequential ACT recurrence: r7 structure + dwordx4 W ------
// 128 blocks x 1024 threads; block owns rows b0, b0+1 at independent
// (t, nstep). Thread (h=tid&511, kh=tid>>9) accumulates k-half kh of column h
// for BOTH rows. W streamed as dwordx4 units (whh4 packing): unit u covers
// k = kh*256 + 4u .. +4, giving wv.x..wv.w == r7's w0..w3 -> FMA association
// token-identical to r7 (chain c = u&3, ascending u) -> bitwise-same outputs.
// s broadcast from LDS ping-pong (r7-proven). 3 barriers/pass.
__global__ __launch_bounds__(1024, 1) void k_recur9(
    const float* __restrict__ x,      // [T,B,256]
    const float* __restrict__ wihT,   // [256][512]
    const float* __restrict__ whh4,   // [128][512] float4 units
    const float* __restrict__ W_ih,   // flag col at [h*257+256]
    const float* __restrict__ w_halt,
    const float* __restrict__ b_ih,
    const float* __restrict__ b_hh,
    const float* __restrict__ b_halt,
    float* out,                       // d_out (y region reused as bf16 s_acc)
    float* __restrict__ psum_g)       // [T*B]
{
    __shared__ __align__(16) float sb[2][2][H_DIM];    // [row][pingpong][k]
    __shared__ __align__(16) float xcw[2][WIN][H_DIM]; // [row][tw][h]  64 KB
    __shared__ float prt[2][2][H_DIM];                 // [kh][row][h]
    __shared__ __align__(16) float xst[WIN * D_DIM];   // 16 KB
    __shared__ float whalt_l[H_DIM];
    __shared__ float flag_l[H_DIM];
    __shared__ float bias_l[H_DIM];
    __shared__ float red[16];

    const int tid = threadIdx.x;
    const int h = tid & 511;
    const int kh = tid >> 9;
    const int b0 = blockIdx.x * 2;
    const int wave = tid >> 6;       // row0: 0..7, row1: 8..15
    const int lane = tid & 63;

    if (!kh) {
        whalt_l[h] = w_halt[h];
        flag_l[h] = W_ih[h * 257 + 256];
        bias_l[h] = b_ih[h] + b_hh[h];
    }
    sb[kh][0][h] = 0.f;

    const float bh = b_halt[0];
    const float THR = 1.0f - 0.01f;
    unsigned short* sacc_out = (unsigned short*)out;
    float* rho_out = out + (size_t)T_DIM * B_DIM * O_DIM;
    float* n_out = rho_out + (size_t)T_DIM * B_DIM;

    // W unit pointer: unit u at w4[u*512] = float4{W_hh[h][kh*256+4u .. +4)}
    const float4* w4 = (const float4*)whh4 + (size_t)kh * 64 * 512 + h;

    int t0 = 0, t1 = 0, nst0 = 0, nst1 = 0, cur0 = 0, cur1 = 0;
    int act0 = 1, act1 = 1;
    float hsum0 = 0.f, runf0 = 1.f, steps0 = 0.f, rem0 = 0.f, ps0 = 0.f;
    float hsum1 = 0.f, runf1 = 1.f, steps1 = 0.f, rem1 = 0.f, ps1 = 0.f;
    float sacc_v = 0.f;
    int refill0 = 1, refill1 = 1;

#define DO_REFILL(RROW, TB, BR)                                               \
    {                                                                         \
        __syncthreads();                                                      \
        for (int i = tid; i < WIN * D_DIM; i += 1024)                         \
            xst[i] = x[((size_t)((TB) + (i >> 8)) * B_DIM + (BR)) * D_DIM +   \
                       (i & 255)];                                            \
        __syncthreads();                                                      \
        float xa[8];                                                          \
        _Pragma("unroll") for (int jj = 0; jj < 8; ++jj) xa[jj] = 0.f;        \
        for (int d = 0; d < 256; d += 4) {                                    \
            const float u0 = wihT[(d + 0) * 512 + h];                         \
            const float u1 = wihT[(d + 1) * 512 + h];                         \
            const float u2 = wihT[(d + 2) * 512 + h];                         \
            const float u3 = wihT[(d + 3) * 512 + h];                         \
            _Pragma("unroll") for (int jj = 0; jj < 8; ++jj) {                \
                const float4 xv =                                             \
                    *(const float4*)&xst[(kh * 8 + jj) * 256 + d];            \
                xa[jj] += xv.x * u0;                                          \
                xa[jj] += xv.y * u1;                                          \
                xa[jj] += xv.z * u2;                                          \
                xa[jj] += xv.w * u3;                                          \
            }                                                                 \
        }                                                                     \
        _Pragma("unroll") for (int jj = 0; jj < 8; ++jj)                      \
            xcw[RROW][kh * 8 + jj][h] = xa[jj] + bias_l[h];                   \
        __syncthreads();                                                      \
    }

    DO_REFILL(0, 0, b0)
    DO_REFILL(1, 0, b0 + 1)

    while (act0 || act1) {
        // ---- phase 1: dwordx4 W stream x LDS-broadcast s, both rows ----
        // Association == r7: unit u covers k = 4u..4u+3 of this k-half;
        // chain c = u&3; wv.x..wv.w == r7's w0..w3; ascending u.
        const float4* s4_0 = (const float4*)&sb[0][cur0][kh << 8];
        const float4* s4_1 = (const float4*)&sb[1][cur1][kh << 8];
        float4 A0[4], A1[4];
#pragma unroll
        for (int c = 0; c < 4; ++c) {
            A0[c] = float4{0.f, 0.f, 0.f, 0.f};
            A1[c] = float4{0.f, 0.f, 0.f, 0.f};
        }
#pragma unroll
        for (int u = 0; u < 64; ++u) {
            const int c = u & 3;
            const float4 wv = w4[(size_t)u * 512];
            const float4 sv0 = s4_0[u];
            const float4 sv1 = s4_1[u];
            A0[c].x += sv0.x * wv.x; A0[c].y += sv0.y * wv.y;
            A0[c].z += sv0.z * wv.z; A0[c].w += sv0.w * wv.w;
            A1[c].x += sv1.x * wv.x; A1[c].y += sv1.y * wv.y;
            A1[c].z += sv1.z * wv.z; A1[c].w += sv1.w * wv.w;
        }
        {
            const float g0 = (A0[0].x + A0[0].y) + (A0[0].z + A0[0].w);
            const float g1 = (A0[1].x + A0[1].y) + (A0[1].z + A0[1].w);
            const float g2 = (A0[2].x + A0[2].y) + (A0[2].z + A0[2].w);
            const float g3 = (A0[3].x + A0[3].y) + (A0[3].z + A0[3].w);
            prt[kh][0][h] = (g0 + g1) + (g2 + g3);
        }
        {
            const float g0 = (A1[0].x + A1[0].y) + (A1[0].z + A1[0].w);
            const float g1 = (A1[1].x + A1[1].y) + (A1[1].z + A1[1].w);
            const float g2 = (A1[2].x + A1[2].y) + (A1[2].z + A1[2].w);
            const float g3 = (A1[3].x + A1[3].y) + (A1[3].z + A1[3].w);
            prt[kh][1][h] = (g0 + g1) + (g2 + g3);
        }
        __syncthreads();   // A: partials ready; sb fully consumed

        // ---- phase 2: row kh post-processing by this half ----
        const int myact = kh ? act1 : act0;
        const int mynst = kh ? nst1 : nst0;
        const int mytw = (kh ? t1 : t0) & (WIN - 1);
        float sn = 0.f;
        if (myact) {
            float base = xcw[kh][mytw][h];
            if (mynst == 0) base += flag_l[h];
            const float pre = (base + prt[0][kh][h]) + prt[1][kh][h];
            sn = tanhf(pre);
            sb[kh][(kh ? cur1 : cur0) ^ 1][h] = sn;
            float pt = sn * whalt_l[h];
#pragma unroll
            for (int m = 1; m < 64; m <<= 1) pt += __shfl_xor(pt, m, 64);
            if (lane == 0) red[wave] = pt;
        }
        __syncthreads();   // B: s-next + red ready

        // ---- phase 3: halting scalars, replicated on all threads ----
        int adv0 = 0, adv1 = 0;
        float p_mine = 0.f;
        if (act0) {
            const float dotv = ((red[0] + red[1]) + (red[2] + red[3])) +
                               ((red[4] + red[5]) + (red[6] + red[7]));
            const float z = dotv + bh;
            const float hn = 1.f / (1.f + expf(-z));
            const float ns = hsum0 + hn;
            const float stop = (ns >= THR) ? runf0 : 0.f;
            const float still = runf0 - stop;
            const float rem = (1.f - hsum0) * stop;
            const float p = hn * still + rem;
            if (kh == 0) p_mine = p;
            ps0 += p; steps0 += runf0; rem0 += rem;
            hsum0 = ns; runf0 = still; cur0 ^= 1; nst0 += 1;
            adv0 = (still == 0.f) || (nst0 == NSTEP);
        }
        if (act1) {
            const float dotv = ((red[8] + red[9]) + (red[10] + red[11])) +
                               ((red[12] + red[13]) + (red[14] + red[15]));
            const float z = dotv + bh;
            const float hn = 1.f / (1.f + expf(-z));
            const float ns = hsum1 + hn;
            const float stop = (ns >= THR) ? runf1 : 0.f;
            const float still = runf1 - stop;
            const float rem = (1.f - hsum1) * stop;
            const float p = hn * still + rem;
            if (kh == 1) p_mine = p;
            ps1 += p; steps1 += runf1; rem1 += rem;
            hsum1 = ns; runf1 = still; cur1 ^= 1; nst1 += 1;
            adv1 = (still == 0.f) || (nst1 == NSTEP);
        }
        if (myact) sacc_v += p_mine * sn;

        // ---- phase 4: per-row advance ----
        const int myadv = kh ? adv1 : adv0;
        if (myadv) {
            const int myt = kh ? t1 : t0;
            sb[kh][kh ? cur1 : cur0][h] = sacc_v;   // s(next t) = s_acc
            sacc_out[((size_t)myt * B_DIM + b0 + kh) * (size_t)H_DIM + h] =
                f2bf(sacc_v);
            if (h == 0) {
                const int bi = myt * B_DIM + b0 + kh;
                psum_g[bi] = kh ? ps1 : ps0;
                rho_out[bi] = (kh ? steps1 + rem1 : steps0 + rem0);
                n_out[bi] = kh ? steps1 : steps0;
            }
            sacc_v = 0.f;
        }
        if (adv0) {
            hsum0 = 0.f; runf0 = 1.f; steps0 = 0.f; rem0 = 0.f; ps0 = 0.f;
            nst0 = 0; t0 += 1;
            if (t0 == T_DIM) act0 = 0;
            else if ((t0 & (WIN - 1)) == 0) refill0 = 1;
        }
        if (adv1) {
            hsum1 = 0.f; runf1 = 1.f; steps1 = 0.f; rem1 = 0.f; ps1 = 0.f;
            nst1 = 0; t1 += 1;
            if (t1 == T_DIM) act1 = 0;
            else if ((t1 & (WIN - 1)) == 0) refill1 = 1;
        }
        __syncthreads();   // C: sb/sacc writes visible before next stream

        if (refill0 && act0) DO_REFILL(0, t0, b0)
        if (refill1 && act1) DO_REFILL(1, t1, b0 + 1)
        refill0 = 0;
        refill1 = 0;
    }
#undef DO_REFILL
}

// ---------------- y = s_acc @ W_out.T + psum * b_out ----------------
__global__ __launch_bounds__(256) void k_y(
    const float* __restrict__ woutT,  // [512][256]
    const float* __restrict__ b_out,
    const float* __restrict__ psum_g,
    float* out)
{
    __shared__ float sl[16][512];
    __shared__ float pl[16];
    const int tid = threadIdx.x;
    const int tb0 = blockIdx.x * 16;
    const unsigned short* sacc = (const unsigned short*)out;
    for (int i = tid; i < 16 * 512; i += 256) {
        unsigned int u = sacc[(size_t)tb0 * 512 + i];
        u <<= 16;
        sl[i >> 9][i & 511] = __uint_as_float(u);
    }
    if (tid < 16) pl[tid] = psum_g[tb0 + tid];
    __syncthreads();
    const int o = tid;
    float acc[16];
#pragma unroll
    for (int r = 0; r < 16; ++r) acc[r] = 0.f;
    for (int hh = 0; hh < 512; hh += 4) {
        const float wv0 = woutT[(hh + 0) * 256 + o];
        const float wv1 = woutT[(hh + 1) * 256 + o];
        const float wv2 = woutT[(hh + 2) * 256 + o];
        const float wv3 = woutT[(hh + 3) * 256 + o];
#pragma unroll
        for (int r = 0; r < 16; ++r) {
            const float4 sv = *(const float4*)&sl[r][hh];
            acc[r] += sv.x * wv0;
            acc[r] += sv.y * wv1;
            acc[r] += sv.z * wv2;
            acc[r] += sv.w * wv3;
        }
    }
    const float bo = b_out[o];
    for (int r = 0; r < 16; ++r)
        out[(size_t)(tb0 + r) * 256 + o] = acc[r] + pl[r] * bo;
}

extern "C" void kernel_launch(void* const* d_in, const int* in_sizes, int n_in,
                              void* d_out, int out_size, void* d_ws, size_t ws_size,
                              hipStream_t stream) {
    const float* x = (const float*)d_in[0];
    const float* W_ih = (const float*)d_in[1];
    const float* b_ih = (const float*)d_in[2];
    const float* W_hh = (const float*)d_in[3];
    const float* b_hh = (const float*)d_in[4];
    const float* W_halt = (const float*)d_in[5];
    const float* b_halt = (const float*)d_in[6];
    const float* W_out = (const float*)d_in[7];
    const float* b_out = (const float*)d_in[8];
    float* out = (float*)d_out;

    char* ws = (char*)d_ws;
    float* whh4 = (float*)ws;                                 // 1 MB
    float* wihT = (float*)(ws + (1u << 20));                  // 512 KB
    float* woutT = (float*)(ws + (1u << 20) + (512u << 10));  // 512 KB
    float* psum = (float*)(ws + (2u << 20));                  // 512 KB

    hipLaunchKernelGGL(k_prep, dim3(2048), dim3(256), 0, stream,
                       W_hh, W_ih, W_out, whh4, wihT, woutT);
    hipLaunchKernelGGL(k_recur9, dim3(B_DIM / 2), dim3(1024), 0, stream,
                       x, wihT, whh4, W_ih, W_halt, b_ih, b_hh, b_halt,
                       out, psum);
    hipLaunchKernelGGL(k_y, dim3((T_DIM * B_DIM) / 16), dim3(256), 0, stream,
                       woutT, b_out, psum, out);
}

// Round 11
// 11105.372 us; speedup vs baseline: 4.2901x; 2.8439x over previous
//
#include <hip/hip_runtime.h>
#include <hip/hip_bf16.h>
#include <cstdint>
#include <cstddef>

#define T_DIM 512
#define B_DIM 256
#define D_DIM 256
#define H_DIM 512
#define O_DIM 256
#define NSTEP 10
#define WIN 16

__device__ __forceinline__ unsigned short f2bf(float f) {
    __hip_bfloat16 b = __float2bfloat16(f);   // RNE
    return *reinterpret_cast<unsigned short*>(&b);
}

// ---------------- transposes (tiny) ----------------
__global__ void k_transpose(const float* __restrict__ W_hh,
                            const float* __restrict__ W_ih,
                            const float* __restrict__ W_out,
                            float* __restrict__ whhT,   // [512][512] k-major
                            float* __restrict__ wihT,   // [256][512] d-major
                            float* __restrict__ woutT)  // [512][256] h-major
{
    int idx = blockIdx.x * blockDim.x + threadIdx.x;
    if (idx < 512 * 512) {
        int k = idx >> 9, h = idx & 511;
        whhT[k * 512 + h] = W_hh[h * 512 + k];
    } else if (idx < 512 * 512 + 256 * 512) {
        int j = idx - 512 * 512;
        int d = j >> 9, h = j & 511;
        wihT[d * 512 + h] = W_ih[h * 257 + d];   // W_ih row length = 257
    } else if (idx < 512 * 512 + 256 * 512 + 512 * 256) {
        int j = idx - (512 * 512 + 256 * 512);
        int h = j >> 8, o = j & 255;
        woutT[h * 256 + o] = W_out[o * 512 + h];
    }
}

// ---------------- sequential ACT recurrence: 1 row per block ---------------
// 256 blocks x 1024 threads; block b owns batch row b; ~1 block/CU, all 256
// CUs busy. Thread (h=tid&511, kh=tid>>9) accumulates k-half kh of column h.
// W streamed k-major scalar-dword (r7-proven: coalesced 256B/wave-instr, no
// register buffer, no spill). Pass count per block = sum_t steps(t) for its
// row — identical to r7's per-block pass count (rows were already decoupled),
// but per-pass VALU/DS/tail work is HALVED and CU count doubled.
// All summation trees token-identical to r7 -> bitwise-identical outputs.
__global__ __launch_bounds__(1024, 1) void k_recur10(
    const float* __restrict__ x,      // [T,B,256]
    const float* __restrict__ wihT,   // [256][512]
    const float* __restrict__ whhT,   // [512][512] k-major
    const float* __restrict__ W_ih,   // flag col at [h*257+256]
    const float* __restrict__ w_halt,
    const float* __restrict__ b_ih,
    const float* __restrict__ b_hh,
    const float* __restrict__ b_halt,
    float* out,                       // d_out (y region reused as bf16 s_acc)
    float* __restrict__ psum_g)       // [T*B]
{
    __shared__ __align__(16) float sb[2][H_DIM];     // s ping-pong  4 KB
    __shared__ __align__(16) float xcw[WIN][H_DIM];  // xc window   32 KB
    __shared__ float prt1[H_DIM];                    // kh=1 partial  2 KB
    __shared__ __align__(16) float xst[WIN * D_DIM]; // staging     16 KB
    __shared__ float whalt_l[H_DIM];
    __shared__ float flag_l[H_DIM];
    __shared__ float bias_l[H_DIM];
    __shared__ float red[8];

    const int tid = threadIdx.x;
    const int h = tid & 511;
    const int kh = tid >> 9;
    const int b = blockIdx.x;
    const int wave = tid >> 6;       // kh=0 half: waves 0..7
    const int lane = tid & 63;

    if (!kh) {
        whalt_l[h] = w_halt[h];
        flag_l[h] = W_ih[h * 257 + 256];
        bias_l[h] = b_ih[h] + b_hh[h];
        sb[0][h] = 0.f;
    }

    const float bh = b_halt[0];
    const float THR = 1.0f - 0.01f;
    unsigned short* sacc_out = (unsigned short*)out;
    float* rho_out = out + (size_t)T_DIM * B_DIM * O_DIM;
    float* n_out = rho_out + (size_t)T_DIM * B_DIM;

    // W column pointer: element k_local at wc[k_local*512]
    //   == W_hh[h][kh*256 + k_local].
    const float* wc = whhT + (size_t)kh * 256 * 512 + h;

    // replicated row state (uniform across the block)
    int t = 0, nst = 0, cur = 0;
    float hsum = 0.f, runf = 1.f, stepsf = 0.f, remf = 0.f, ps = 0.f;
    float sacc_v = 0.f;   // kh=0 threads: column h accumulator

    // refill: stage x[tb..tb+WIN)[b][:], windowed xc GEMM.
    // Token-identical to r7's DO_REFILL (16 j's split 8/8 across kh halves).
#define DO_REFILL(TB)                                                         \
    {                                                                         \
        __syncthreads();                                                      \
        for (int i = tid; i < WIN * D_DIM; i += 1024)                         \
            xst[i] = x[((size_t)((TB) + (i >> 8)) * B_DIM + b) * D_DIM +      \
                       (i & 255)];                                            \
        __syncthreads();                                                      \
        float xa[8];                                                          \
        _Pragma("unroll") for (int jj = 0; jj < 8; ++jj) xa[jj] = 0.f;        \
        for (int d = 0; d < 256; d += 4) {                                    \
            const float u0 = wihT[(d + 0) * 512 + h];                         \
            const float u1 = wihT[(d + 1) * 512 + h];                         \
            const float u2 = wihT[(d + 2) * 512 + h];                         \
            const float u3 = wihT[(d + 3) * 512 + h];                         \
            _Pragma("unroll") for (int jj = 0; jj < 8; ++jj) {                \
                const float4 xv =                                             \
                    *(const float4*)&xst[(kh * 8 + jj) * 256 + d];            \
                xa[jj] += xv.x * u0;                                          \
                xa[jj] += xv.y * u1;                                          \
                xa[jj] += xv.z * u2;                                          \
                xa[jj] += xv.w * u3;                                          \
            }                                                                 \
        }                                                                     \
        _Pragma("unroll") for (int jj = 0; jj < 8; ++jj)                      \
            xcw[kh * 8 + jj][h] = xa[jj] + bias_l[h];                         \
        __syncthreads();                                                      \
    }

    DO_REFILL(0)

    for (;;) {
        // ---- phase 1: coalesced W stream x LDS-broadcast s ----
        // Association == r7: chain A_c consumes k in [16i+4c, 16i+4c+4),
        // ascending i; elementwise x,y,z,w. Single fma chain per chain c.
        const float* sp = &sb[cur][kh << 8];
        float4 A[4];
#pragma unroll
        for (int c = 0; c < 4; ++c) A[c] = float4{0.f, 0.f, 0.f, 0.f};
#pragma unroll 4
        for (int i = 0; i < 16; ++i) {
#pragma unroll
            for (int c = 0; c < 4; ++c) {
                const int kbase = i * 16 + c * 4;
                const float4 sv = *(const float4*)&sp[kbase];
                const float w0 = wc[(size_t)(kbase + 0) * 512];
                const float w1 = wc[(size_t)(kbase + 1) * 512];
                const float w2 = wc[(size_t)(kbase + 2) * 512];
                const float w3 = wc[(size_t)(kbase + 3) * 512];
                A[c].x += sv.x * w0;
                A[c].y += sv.y * w1;
                A[c].z += sv.z * w2;
                A[c].w += sv.w * w3;
            }
        }
        const float g0 = (A[0].x + A[0].y) + (A[0].z + A[0].w);
        const float g1 = (A[1].x + A[1].y) + (A[1].z + A[1].w);
        const float g2 = (A[2].x + A[2].y) + (A[2].z + A[2].w);
        const float g3 = (A[3].x + A[3].y) + (A[3].z + A[3].w);
        const float pd = (g0 + g1) + (g2 + g3);

        if (kh) prt1[h] = pd;
        __syncthreads();   // A: kh=1 partial ready; sb[cur] fully consumed

        // ---- phase 2: kh=0 half post-processes the row ----
        float sn = 0.f;
        if (!kh) {
            float base = xcw[t & (WIN - 1)][h];
            if (nst == 0) base += flag_l[h];
            const float pre = (base + pd) + prt1[h];   // == r7's (b+p0)+p1
            sn = tanhf(pre);
            sb[cur ^ 1][h] = sn;
            float pt = sn * whalt_l[h];
#pragma unroll
            for (int m = 1; m < 64; m <<= 1) pt += __shfl_xor(pt, m, 64);
            if (lane == 0) red[wave] = pt;
        }
        __syncthreads();   // B: s-next + red ready

        // ---- phase 3: halting scalars, replicated on all threads ----
        const float dotv = ((red[0] + red[1]) + (red[2] + red[3])) +
                           ((red[4] + red[5]) + (red[6] + red[7]));
        const float z = dotv + bh;
        const float hn = 1.f / (1.f + expf(-z));
        const float ns = hsum + hn;
        const float stop = (ns >= THR) ? runf : 0.f;
        const float still = runf - stop;
        const float rem = (1.f - hsum) * stop;
        const float p = hn * still + rem;
        ps += p;
        stepsf += runf;   // old running, matches reference order
        remf += rem;
        hsum = ns;
        runf = still;
        nst += 1;
        if (!kh) sacc_v += p * sn;
        cur ^= 1;
        const int adv = (still == 0.f) || (nst == NSTEP);

        // ---- phase 4: advance ----
        if (adv) {
            if (!kh) {
                sb[cur][h] = sacc_v;   // s(next t) = s_acc
                sacc_out[((size_t)t * B_DIM + b) * (size_t)H_DIM + h] =
                    f2bf(sacc_v);
            }
            if (tid == 0) {
                const int bi = t * B_DIM + b;
                psum_g[bi] = ps;
                rho_out[bi] = stepsf + remf;
                n_out[bi] = stepsf;
            }
            hsum = 0.f; runf = 1.f; stepsf = 0.f; remf = 0.f; ps = 0.f;
            nst = 0; sacc_v = 0.f;
            t += 1;
        }
        __syncthreads();   // C: sb/sacc writes visible before next stream

        if (adv) {
            if (t == T_DIM) break;                    // uniform
            if ((t & (WIN - 1)) == 0) DO_REFILL(t)
        }
    }
#undef DO_REFILL
}

// ---------------- y = s_acc @ W_out.T + psum * b_out ----------------
__global__ __launch_bounds__(256) void k_y(
    const float* __restrict__ woutT,  // [512][256]
    const float* __restrict__ b_out,
    const float* __restrict__ psum_g,
    float* out)
{
    __shared__ float sl[16][512];
    __shared__ float pl[16];
    const int tid = threadIdx.x;
    const int tb0 = blockIdx.x * 16;
    const unsigned short* sacc = (const unsigned short*)out;
    for (int i = tid; i < 16 * 512; i += 256) {
        unsigned int u = sacc[(size_t)tb0 * 512 + i];
        u <<= 16;
        sl[i >> 9][i & 511] = __uint_as_float(u);
    }
    if (tid < 16) pl[tid] = psum_g[tb0 + tid];
    __syncthreads();
    const int o = tid;
    float acc[16];
#pragma unroll
    for (int r = 0; r < 16; ++r) acc[r] = 0.f;
    for (int hh = 0; hh < 512; hh += 4) {
        const float wv0 = woutT[(hh + 0) * 256 + o];
        const float wv1 = woutT[(hh + 1) * 256 + o];
        const float wv2 = woutT[(hh + 2) * 256 + o];
        const float wv3 = woutT[(hh + 3) * 256 + o];
#pragma unroll
        for (int r = 0; r < 16; ++r) {
            const float4 sv = *(const float4*)&sl[r][hh];
            acc[r] += sv.x * wv0;
            acc[r] += sv.y * wv1;
            acc[r] += sv.z * wv2;
            acc[r] += sv.w * wv3;
        }
    }
    const float bo = b_out[o];
    for (int r = 0; r < 16; ++r)
        out[(size_t)(tb0 + r) * 256 + o] = acc[r] + pl[r] * bo;
}

extern "C" void kernel_launch(void* const* d_in, const int* in_sizes, int n_in,
                              void* d_out, int out_size, void* d_ws, size_t ws_size,
                              hipStream_t stream) {
    const float* x = (const float*)d_in[0];
    const float* W_ih = (const float*)d_in[1];
    const float* b_ih = (const float*)d_in[2];
    const float* W_hh = (const float*)d_in[3];
    const float* b_hh = (const float*)d_in[4];
    const float* W_halt = (const float*)d_in[5];
    const float* b_halt = (const float*)d_in[6];
    const float* W_out = (const float*)d_in[7];
    const float* b_out = (const float*)d_in[8];
    float* out = (float*)d_out;

    char* ws = (char*)d_ws;
    float* whhT = (float*)ws;                                 // 1 MB
    float* wihT = (float*)(ws + (1u << 20));                  // 512 KB
    float* woutT = (float*)(ws + (1u << 20) + (512u << 10));  // 512 KB
    float* psum = (float*)(ws + (2u << 20));                  // 512 KB

    hipLaunchKernelGGL(k_transpose, dim3(2048), dim3(256), 0, stream,
                       W_hh, W_ih, W_out, whhT, wihT, woutT);
    hipLaunchKernelGGL(k_recur10, dim3(B_DIM), dim3(1024), 0, stream,
                       x, wihT, whhT, W_ih, W_halt, b_ih, b_hh, b_halt,
                       out, psum);
    hipLaunchKernelGGL(k_y, dim3((T_DIM * B_DIM) / 16), dim3(256), 0, stream,
                       woutT, b_out, psum, out);
}

// Round 12
// 10481.189 us; speedup vs baseline: 4.5456x; 1.0596x over previous
//
#include <hip/hip_runtime.h>
#include <hip/hip_bf16.h>
#include <cstdint>
#include <cstddef>

#define T_DIM 512
#define B_DIM 256
#define D_DIM 256
#define H_DIM 512
#define O_DIM 256
#define NSTEP 10
#define WIN 16

__device__ __forceinline__ unsigned short f2bf(float f) {
    __hip_bfloat16 b = __float2bfloat16(f);   // RNE
    return *reinterpret_cast<unsigned short*>(&b);
}

// ---------------- prep: W float4-unit packing + transposes ----------------
// whh4 unit layout: ((float4*)whh4)[q*512+h]
//   = float4{ W_hh[h][4q], W_hh[h][4q+1], W_hh[h][4q+2], W_hh[h][4q+3] }
// -> thread streaming column h reads lane-coalesced dwordx4 (1 KB/wave-instr).
__global__ void k_prep(const float* __restrict__ W_hh,
                       const float* __restrict__ W_ih,
                       const float* __restrict__ W_out,
                       float* __restrict__ whh4,   // [128][512] float4 units
                       float* __restrict__ wihT,   // [256][512] d-major
                       float* __restrict__ woutT)  // [512][256] h-major
{
    int idx = blockIdx.x * blockDim.x + threadIdx.x;
    if (idx < 65536) {
        int q = idx >> 9, h = idx & 511;
        ((float4*)whh4)[q * 512 + h] = ((const float4*)W_hh)[h * 128 + q];
    } else if (idx < 65536 + 131072) {
        int j = idx - 65536;
        int d = j >> 9, h = j & 511;
        wihT[d * 512 + h] = W_ih[h * 257 + d];   // W_ih row length = 257
    } else if (idx < 65536 + 131072 + 131072) {
        int j = idx - (65536 + 131072);
        int h = j >> 8, o = j & 255;
        woutT[h * 256 + o] = W_out[o * 512 + h];
    }
}

// ---------------- sequential ACT recurrence: 1 row/block, dwordx4 W -------
// 256 blocks x 1024 threads; block b owns batch row b. Thread (h=tid&511,
// kh=tid>>9) accumulates k-half kh of column h. W streamed as packed dwordx4
// units (whh4): unit j covers k = kh*256+4j..+3, so wv.x..wv.w == r10's
// w0..w3 at kbase=4j; chain c = j&3, ascending j -> FMA sequence token-
// identical to r10 -> bitwise-identical outputs. unroll 4 keeps <=4 float4
// W temps live (r9's spill came from its fully-unrolled body, not layout).
// Barrier C is skipped on non-advance passes: on those passes the only
// cross-phase LDS writes the next pass reads (sb[cur] from phase 2, red)
// are already ordered by barriers A/B; the sacc overwrite of sb needs the
// barrier only when the row advances.
__global__ __launch_bounds__(1024, 1) void k_recur11(
    const float* __restrict__ x,      // [T,B,256]
    const float* __restrict__ wihT,   // [256][512]
    const float* __restrict__ whh4,   // [128][512] float4 units
    const float* __restrict__ W_ih,   // flag col at [h*257+256]
    const float* __restrict__ w_halt,
    const float* __restrict__ b_ih,
    const float* __restrict__ b_hh,
    const float* __restrict__ b_halt,
    float* out,                       // d_out (y region reused as bf16 s_acc)
    float* __restrict__ psum_g)       // [T*B]
{
    __shared__ __align__(16) float sb[2][H_DIM];     // s ping-pong  4 KB
    __shared__ __align__(16) float xcw[WIN][H_DIM];  // xc window   32 KB
    __shared__ float prt1[H_DIM];                    // kh=1 partial  2 KB
    __shared__ __align__(16) float xst[WIN * D_DIM]; // staging     16 KB
    __shared__ float whalt_l[H_DIM];
    __shared__ float flag_l[H_DIM];
    __shared__ float bias_l[H_DIM];
    __shared__ float red[8];

    const int tid = threadIdx.x;
    const int h = tid & 511;
    const int kh = tid >> 9;
    const int b = blockIdx.x;
    const int wave = tid >> 6;       // kh=0 half: waves 0..7
    const int lane = tid & 63;

    if (!kh) {
        whalt_l[h] = w_halt[h];
        flag_l[h] = W_ih[h * 257 + 256];
        bias_l[h] = b_ih[h] + b_hh[h];
        sb[0][h] = 0.f;
    }

    const float bh = b_halt[0];
    const float THR = 1.0f - 0.01f;
    unsigned short* sacc_out = (unsigned short*)out;
    float* rho_out = out + (size_t)T_DIM * B_DIM * O_DIM;
    float* n_out = rho_out + (size_t)T_DIM * B_DIM;

    // W unit pointer: unit j at w4[j*512] = float4{W_hh[h][kh*256+4j .. +4)}
    const float4* w4 = (const float4*)whh4 + (size_t)kh * 64 * 512 + h;

    // replicated row state (uniform across the block)
    int t = 0, nst = 0, cur = 0;
    float hsum = 0.f, runf = 1.f, stepsf = 0.f, remf = 0.f, ps = 0.f;
    float sacc_v = 0.f;   // kh=0 threads: column h accumulator

    // refill: stage x[tb..tb+WIN)[b][:], windowed xc GEMM.
    // Token-identical to r10's DO_REFILL.
#define DO_REFILL(TB)                                                         \
    {                                                                         \
        __syncthreads();                                                      \
        for (int i = tid; i < WIN * D_DIM; i += 1024)                         \
            xst[i] = x[((size_t)((TB) + (i >> 8)) * B_DIM + b) * D_DIM +      \
                       (i & 255)];                                            \
        __syncthreads();                                                      \
        float xa[8];                                                          \
        _Pragma("unroll") for (int jj = 0; jj < 8; ++jj) xa[jj] = 0.f;        \
        for (int d = 0; d < 256; d += 4) {                                    \
            const float u0 = wihT[(d + 0) * 512 + h];                         \
            const float u1 = wihT[(d + 1) * 512 + h];                         \
            const float u2 = wihT[(d + 2) * 512 + h];                         \
            const float u3 = wihT[(d + 3) * 512 + h];                         \
            _Pragma("unroll") for (int jj = 0; jj < 8; ++jj) {                \
                const float4 xv =                                             \
                    *(const float4*)&xst[(kh * 8 + jj) * 256 + d];            \
                xa[jj] += xv.x * u0;                                          \
                xa[jj] += xv.y * u1;                                          \
                xa[jj] += xv.z * u2;                                          \
                xa[jj] += xv.w * u3;                                          \
            }                                                                 \
        }                                                                     \
        _Pragma("unroll") for (int jj = 0; jj < 8; ++jj)                      \
            xcw[kh * 8 + jj][h] = xa[jj] + bias_l[h];                         \
        __syncthreads();                                                      \
    }

    DO_REFILL(0)

    for (;;) {
        // ---- phase 1: dwordx4 W stream x LDS-broadcast s ----
        // j-loop == r10's (i,c) loop flattened: j = 4i+c, kbase = 4j.
        const float4* s4 = (const float4*)&sb[cur][kh << 8];
        float4 A[4];
#pragma unroll
        for (int c = 0; c < 4; ++c) A[c] = float4{0.f, 0.f, 0.f, 0.f};
#pragma unroll 4
        for (int j = 0; j < 64; ++j) {
            const int c = j & 3;
            const float4 wv = w4[(size_t)j * 512];
            const float4 sv = s4[j];
            A[c].x += sv.x * wv.x;
            A[c].y += sv.y * wv.y;
            A[c].z += sv.z * wv.z;
            A[c].w += sv.w * wv.w;
        }
        const float g0 = (A[0].x + A[0].y) + (A[0].z + A[0].w);
        const float g1 = (A[1].x + A[1].y) + (A[1].z + A[1].w);
        const float g2 = (A[2].x + A[2].y) + (A[2].z + A[2].w);
        const float g3 = (A[3].x + A[3].y) + (A[3].z + A[3].w);
        const float pd = (g0 + g1) + (g2 + g3);

        if (kh) prt1[h] = pd;
        __syncthreads();   // A: kh=1 partial ready; sb[cur] fully consumed

        // ---- phase 2: kh=0 half post-processes the row ----
        float sn = 0.f;
        if (!kh) {
            float base = xcw[t & (WIN - 1)][h];
            if (nst == 0) base += flag_l[h];
            const float pre = (base + pd) + prt1[h];   // == r10
            sn = tanhf(pre);
            sb[cur ^ 1][h] = sn;
            float pt = sn * whalt_l[h];
#pragma unroll
            for (int m = 1; m < 64; m <<= 1) pt += __shfl_xor(pt, m, 64);
            if (lane == 0) red[wave] = pt;
        }
        __syncthreads();   // B: s-next + red ready

        // ---- phase 3: halting scalars, replicated on all threads ----
        const float dotv = ((red[0] + red[1]) + (red[2] + red[3])) +
                           ((red[4] + red[5]) + (red[6] + red[7]));
        const float z = dotv + bh;
        const float hn = 1.f / (1.f + expf(-z));
        const float ns = hsum + hn;
        const float stop = (ns >= THR) ? runf : 0.f;
        const float still = runf - stop;
        const float rem = (1.f - hsum) * stop;
        const float p = hn * still + rem;
        ps += p;
        stepsf += runf;   // old running, matches reference order
        remf += rem;
        hsum = ns;
        runf = still;
        nst += 1;
        if (!kh) sacc_v += p * sn;
        cur ^= 1;
        const int adv = (still == 0.f) || (nst == NSTEP);

        // ---- phase 4: advance (barrier only on adv; see header comment) --
        if (adv) {
            if (!kh) {
                sb[cur][h] = sacc_v;   // s(next t) = s_acc
                sacc_out[((size_t)t * B_DIM + b) * (size_t)H_DIM + h] =
                    f2bf(sacc_v);
            }
            if (tid == 0) {
                const int bi = t * B_DIM + b;
                psum_g[bi] = ps;
                rho_out[bi] = stepsf + remf;
                n_out[bi] = stepsf;
            }
            hsum = 0.f; runf = 1.f; stepsf = 0.f; remf = 0.f; ps = 0.f;
            nst = 0; sacc_v = 0.f;
            t += 1;
            __syncthreads();   // C: sacc overwrite of sb visible to all
            if (t == T_DIM) break;                    // uniform
            if ((t & (WIN - 1)) == 0) DO_REFILL(t)
        }
    }
#undef DO_REFILL
}

// ---------------- y = s_acc @ W_out.T + psum * b_out ----------------
__global__ __launch_bounds__(256) void k_y(
    const float* __restrict__ woutT,  // [512][256]
    const float* __restrict__ b_out,
    const float* __restrict__ psum_g,
    float* out)
{
    __shared__ float sl[16][512];
    __shared__ float pl[16];
    const int tid = threadIdx.x;
    const int tb0 = blockIdx.x * 16;
    const unsigned short* sacc = (const unsigned short*)out;
    for (int i = tid; i < 16 * 512; i += 256) {
        unsigned int u = sacc[(size_t)tb0 * 512 + i];
        u <<= 16;
        sl[i >> 9][i & 511] = __uint_as_float(u);
    }
    if (tid < 16) pl[tid] = psum_g[tb0 + tid];
    __syncthreads();
    const int o = tid;
    float acc[16];
#pragma unroll
    for (int r = 0; r < 16; ++r) acc[r] = 0.f;
    for (int hh = 0; hh < 512; hh += 4) {
        const float wv0 = woutT[(hh + 0) * 256 + o];
        const float wv1 = woutT[(hh + 1) * 256 + o];
        const float wv2 = woutT[(hh + 2) * 256 + o];
        const float wv3 = woutT[(hh + 3) * 256 + o];
#pragma unroll
        for (int r = 0; r < 16; ++r) {
            const float4 sv = *(const float4*)&sl[r][hh];
            acc[r] += sv.x * wv0;
            acc[r] += sv.y * wv1;
            acc[r] += sv.z * wv2;
            acc[r] += sv.w * wv3;
        }
    }
    const float bo = b_out[o];
    for (int r = 0; r < 16; ++r)
        out[(size_t)(tb0 + r) * 256 + o] = acc[r] + pl[r] * bo;
}

extern "C" void kernel_launch(void* const* d_in, const int* in_sizes, int n_in,
                              void* d_out, int out_size, void* d_ws, size_t ws_size,
                              hipStream_t stream) {
    const float* x = (const float*)d_in[0];
    const float* W_ih = (const float*)d_in[1];
    const float* b_ih = (const float*)d_in[2];
    const float* W_hh = (const float*)d_in[3];
    const float* b_hh = (const float*)d_in[4];
    const float* W_halt = (const float*)d_in[5];
    const float* b_halt = (const float*)d_in[6];
    const float* W_out = (const float*)d_in[7];
    const float* b_out = (const float*)d_in[8];
    float* out = (float*)d_out;

    char* ws = (char*)d_ws;
    float* whh4 = (float*)ws;                                 // 1 MB
    float* wihT = (float*)(ws + (1u << 20));                  // 512 KB
    float* woutT = (float*)(ws + (1u << 20) + (512u << 10));  // 512 KB
    float* psum = (float*)(ws + (2u << 20));                  // 512 KB

    hipLaunchKernelGGL(k_prep, dim3(1284), dim3(256), 0, stream,
                       W_hh, W_ih, W_out, whh4, wihT, woutT);
    hipLaunchKernelGGL(k_recur11, dim3(B_DIM), dim3(1024), 0, stream,
                       x, wihT, whh4, W_ih, W_halt, b_ih, b_hh, b_halt,
                       out, psum);
    hipLaunchKernelGGL(k_y, dim3((T_DIM * B_DIM) / 16), dim3(256), 0, stream,
                       woutT, b_out, psum, out);
}

// Round 13
// 10113.943 us; speedup vs baseline: 4.7106x; 1.0363x over previous
//
#include <hip/hip_runtime.h>
#include <hip/hip_bf16.h>
#include <cstdint>
#include <cstddef>

#define T_DIM 512
#define B_DIM 256
#define D_DIM 256
#define H_DIM 512
#define O_DIM 256
#define NSTEP 10
#define WIN 16
#define PFX 6   // W units per k-half resident in LDS (6*2*512*16B = 96 KB)

__device__ __forceinline__ unsigned short f2bf(float f) {
    __hip_bfloat16 b = __float2bfloat16(f);   // RNE
    return *reinterpret_cast<unsigned short*>(&b);
}

// ---------------- prep: W float4-unit packing + transposes ----------------
// whh4 unit layout: ((float4*)whh4)[q*512+h]
//   = float4{ W_hh[h][4q], W_hh[h][4q+1], W_hh[h][4q+2], W_hh[h][4q+3] }
__global__ void k_prep(const float* __restrict__ W_hh,
                       const float* __restrict__ W_ih,
                       const float* __restrict__ W_out,
                       float* __restrict__ whh4,   // [128][512] float4 units
                       float* __restrict__ wihT,   // [256][512] d-major
                       float* __restrict__ woutT)  // [512][256] h-major
{
    int idx = blockIdx.x * blockDim.x + threadIdx.x;
    if (idx < 65536) {
        int q = idx >> 9, h = idx & 511;
        ((float4*)whh4)[q * 512 + h] = ((const float4*)W_hh)[h * 128 + q];
    } else if (idx < 65536 + 131072) {
        int j = idx - 65536;
        int d = j >> 9, h = j & 511;
        wihT[d * 512 + h] = W_ih[h * 257 + d];   // W_ih row length = 257
    } else if (idx < 65536 + 131072 + 131072) {
        int j = idx - (65536 + 131072);
        int h = j >> 8, o = j & 255;
        woutT[h * 256 + o] = W_out[o * 512 + h];
    }
}

// ---------------- sequential ACT recurrence: 1 row/block ------------------
// r11 structure + (a) LDS-persistent W prefix units j=0..PFX-1 (both k-halves,
// staged once; phase 1 reads them via DS pipe, overlapping the L2 stream and
// cutting streamed bytes 9.4%), (b) unroll 8 on the L2 stream (deeper load
// pipelining). FMA order per chain (c = j&3, ascending j) is token-identical
// to r11 -> bitwise-identical outputs.
__global__ __launch_bounds__(1024, 1) void k_recur12(
    const float* __restrict__ x,      // [T,B,256]
    const float* __restrict__ wihT,   // [256][512]
    const float* __restrict__ whh4,   // [128][512] float4 units
    const float* __restrict__ W_ih,   // flag col at [h*257+256]
    const float* __restrict__ w_halt,
    const float* __restrict__ b_ih,
    const float* __restrict__ b_hh,
    const float* __restrict__ b_halt,
    float* out,                       // d_out (y region reused as bf16 s_acc)
    float* __restrict__ psum_g)       // [T*B]
{
    __shared__ __align__(16) float4 wp_l[2 * PFX * 512];  // 96 KB W prefix
    __shared__ __align__(16) float sb[2][H_DIM];     // s ping-pong  4 KB
    __shared__ __align__(16) float xcw[WIN][H_DIM];  // xc window   32 KB
    __shared__ float prt1[H_DIM];                    // kh=1 partial  2 KB
    __shared__ __align__(16) float xst[WIN * D_DIM]; // staging     16 KB
    __shared__ float whalt_l[H_DIM];
    __shared__ float flag_l[H_DIM];
    __shared__ float bias_l[H_DIM];
    __shared__ float red[8];

    const int tid = threadIdx.x;
    const int h = tid & 511;
    const int kh = tid >> 9;
    const int b = blockIdx.x;
    const int wave = tid >> 6;       // kh=0 half: waves 0..7
    const int lane = tid & 63;

    if (!kh) {
        whalt_l[h] = w_halt[h];
        flag_l[h] = W_ih[h * 257 + 256];
        bias_l[h] = b_ih[h] + b_hh[h];
        sb[0][h] = 0.f;
    }
    // stage W prefix: wp_l[kh2*PFX*512 + j*512 + h] = whh4 unit (kh2, j, h)
    for (int i = tid; i < 2 * PFX * 512; i += 1024) {
        const int kh2 = i / (PFX * 512);
        const int rem = i - kh2 * (PFX * 512);
        wp_l[i] = ((const float4*)whh4)[(size_t)kh2 * 64 * 512 + rem];
    }

    const float bh = b_halt[0];
    const float THR = 1.0f - 0.01f;
    unsigned short* sacc_out = (unsigned short*)out;
    float* rho_out = out + (size_t)T_DIM * B_DIM * O_DIM;
    float* n_out = rho_out + (size_t)T_DIM * B_DIM;

    // streamed-W unit pointer: unit j at w4[j*512]
    const float4* w4 = (const float4*)whh4 + (size_t)kh * 64 * 512 + h;
    const float4* wp = &wp_l[kh * PFX * 512 + h];   // prefix, stride 512 units

    // replicated row state (uniform across the block)
    int t = 0, nst = 0, cur = 0;
    float hsum = 0.f, runf = 1.f, stepsf = 0.f, remf = 0.f, ps = 0.f;
    float sacc_v = 0.f;   // kh=0 threads: column h accumulator

#define DO_REFILL(TB)                                                         \
    {                                                                         \
        __syncthreads();                                                      \
        for (int i = tid; i < WIN * D_DIM; i += 1024)                         \
            xst[i] = x[((size_t)((TB) + (i >> 8)) * B_DIM + b) * D_DIM +      \
                       (i & 255)];                                            \
        __syncthreads();                                                      \
        float xa[8];                                                          \
        _Pragma("unroll") for (int jj = 0; jj < 8; ++jj) xa[jj] = 0.f;        \
        for (int d = 0; d < 256; d += 4) {                                    \
            const float u0 = wihT[(d + 0) * 512 + h];                         \
            const float u1 = wihT[(d + 1) * 512 + h];                         \
            const float u2 = wihT[(d + 2) * 512 + h];                         \
            const float u3 = wihT[(d + 3) * 512 + h];                         \
            _Pragma("unroll") for (int jj = 0; jj < 8; ++jj) {                \
                const float4 xv =                                             \
                    *(const float4*)&xst[(kh * 8 + jj) * 256 + d];            \
                xa[jj] += xv.x * u0;                                          \
                xa[jj] += xv.y * u1;                                          \
                xa[jj] += xv.z * u2;                                          \
                xa[jj] += xv.w * u3;                                          \
            }                                                                 \
        }                                                                     \
        _Pragma("unroll") for (int jj = 0; jj < 8; ++jj)                      \
            xcw[kh * 8 + jj][h] = xa[jj] + bias_l[h];                         \
        __syncthreads();                                                      \
    }

    DO_REFILL(0)   // leading __syncthreads also covers wp_l/sb/bias staging

    for (;;) {
        // ---- phase 1: W stream (LDS prefix j<PFX, L2 j>=PFX) x s ----
        // Same per-chain (c=j&3) ascending-j FMA order as r11.
        const float4* s4 = (const float4*)&sb[cur][kh << 8];
        float4 A[4];
#pragma unroll
        for (int c = 0; c < 4; ++c) A[c] = float4{0.f, 0.f, 0.f, 0.f};
#pragma unroll
        for (int j = 0; j < PFX; ++j) {
            const int c = j & 3;
            const float4 wv = wp[j * 512];
            const float4 sv = s4[j];
            A[c].x += sv.x * wv.x;
            A[c].y += sv.y * wv.y;
            A[c].z += sv.z * wv.z;
            A[c].w += sv.w * wv.w;
        }
#pragma unroll 8
        for (int j = PFX; j < 64; ++j) {
            const int c = j & 3;
            const float4 wv = w4[(size_t)j * 512];
            const float4 sv = s4[j];
            A[c].x += sv.x * wv.x;
            A[c].y += sv.y * wv.y;
            A[c].z += sv.z * wv.z;
            A[c].w += sv.w * wv.w;
        }
        const float g0 = (A[0].x + A[0].y) + (A[0].z + A[0].w);
        const float g1 = (A[1].x + A[1].y) + (A[1].z + A[1].w);
        const float g2 = (A[2].x + A[2].y) + (A[2].z + A[2].w);
        const float g3 = (A[3].x + A[3].y) + (A[3].z + A[3].w);
        const float pd = (g0 + g1) + (g2 + g3);

        if (kh) prt1[h] = pd;
        __syncthreads();   // A: kh=1 partial ready; sb[cur] fully consumed

        // ---- phase 2: kh=0 half post-processes the row ----
        float sn = 0.f;
        if (!kh) {
            float base = xcw[t & (WIN - 1)][h];
            if (nst == 0) base += flag_l[h];
            const float pre = (base + pd) + prt1[h];   // == r11
            sn = tanhf(pre);
            sb[cur ^ 1][h] = sn;
            float pt = sn * whalt_l[h];
#pragma unroll
            for (int m = 1; m < 64; m <<= 1) pt += __shfl_xor(pt, m, 64);
            if (lane == 0) red[wave] = pt;
        }
        __syncthreads();   // B: s-next + red ready

        // ---- phase 3: halting scalars, replicated on all threads ----
        const float dotv = ((red[0] + red[1]) + (red[2] + red[3])) +
                           ((red[4] + red[5]) + (red[6] + red[7]));
        const float z = dotv + bh;
        const float hn = 1.f / (1.f + expf(-z));
        const float ns = hsum + hn;
        const float stop = (ns >= THR) ? runf : 0.f;
        const float still = runf - stop;
        const float rem = (1.f - hsum) * stop;
        const float p = hn * still + rem;
        ps += p;
        stepsf += runf;   // old running, matches reference order
        remf += rem;
        hsum = ns;
        runf = still;
        nst += 1;
        if (!kh) sacc_v += p * sn;
        cur ^= 1;
        const int adv = (still == 0.f) || (nst == NSTEP);

        // ---- phase 4: advance (barrier only on adv; r11-proven) ----
        if (adv) {
            if (!kh) {
                sb[cur][h] = sacc_v;   // s(next t) = s_acc
                sacc_out[((size_t)t * B_DIM + b) * (size_t)H_DIM + h] =
                    f2bf(sacc_v);
            }
            if (tid == 0) {
                const int bi = t * B_DIM + b;
                psum_g[bi] = ps;
                rho_out[bi] = stepsf + remf;
                n_out[bi] = stepsf;
            }
            hsum = 0.f; runf = 1.f; stepsf = 0.f; remf = 0.f; ps = 0.f;
            nst = 0; sacc_v = 0.f;
            t += 1;
            __syncthreads();   // C: sacc overwrite of sb visible to all
            if (t == T_DIM) break;                    // uniform
            if ((t & (WIN - 1)) == 0) DO_REFILL(t)
        }
    }
#undef DO_REFILL
}

// ---------------- y = s_acc @ W_out.T + psum * b_out ----------------
__global__ __launch_bounds__(256) void k_y(
    const float* __restrict__ woutT,  // [512][256]
    const float* __restrict__ b_out,
    const float* __restrict__ psum_g,
    float* out)
{
    __shared__ float sl[16][512];
    __shared__ float pl[16];
    const int tid = threadIdx.x;
    const int tb0 = blockIdx.x * 16;
    const unsigned short* sacc = (const unsigned short*)out;
    for (int i = tid; i < 16 * 512; i += 256) {
        unsigned int u = sacc[(size_t)tb0 * 512 + i];
        u <<= 16;
        sl[i >> 9][i & 511] = __uint_as_float(u);
    }
    if (tid < 16) pl[tid] = psum_g[tb0 + tid];
    __syncthreads();
    const int o = tid;
    float acc[16];
#pragma unroll
    for (int r = 0; r < 16; ++r) acc[r] = 0.f;
    for (int hh = 0; hh < 512; hh += 4) {
        const float wv0 = woutT[(hh + 0) * 256 + o];
        const float wv1 = woutT[(hh + 1) * 256 + o];
        const float wv2 = woutT[(hh + 2) * 256 + o];
        const float wv3 = woutT[(hh + 3) * 256 + o];
#pragma unroll
        for (int r = 0; r < 16; ++r) {
            const float4 sv = *(const float4*)&sl[r][hh];
            acc[r] += sv.x * wv0;
            acc[r] += sv.y * wv1;
            acc[r] += sv.z * wv2;
            acc[r] += sv.w * wv3;
        }
    }
    const float bo = b_out[o];
    for (int r = 0; r < 16; ++r)
        out[(size_t)(tb0 + r) * 256 + o] = acc[r] + pl[r] * bo;
}

extern "C" void kernel_launch(void* const* d_in, const int* in_sizes, int n_in,
                              void* d_out, int out_size, void* d_ws, size_t ws_size,
                              hipStream_t stream) {
    const float* x = (const float*)d_in[0];
    const float* W_ih = (const float*)d_in[1];
    const float* b_ih = (const float*)d_in[2];
    const float* W_hh = (const float*)d_in[3];
    const float* b_hh = (const float*)d_in[4];
    const float* W_halt = (const float*)d_in[5];
    const float* b_halt = (const float*)d_in[6];
    const float* W_out = (const float*)d_in[7];
    const float* b_out = (const float*)d_in[8];
    float* out = (float*)d_out;

    char* ws = (char*)d_ws;
    float* whh4 = (float*)ws;                                 // 1 MB
    float* wihT = (float*)(ws + (1u << 20));                  // 512 KB
    float* woutT = (float*)(ws + (1u << 20) + (512u << 10));  // 512 KB
    float* psum = (float*)(ws + (2u << 20));                  // 512 KB

    hipLaunchKernelGGL(k_prep, dim3(1284), dim3(256), 0, stream,
                       W_hh, W_ih, W_out, whh4, wihT, woutT);
    hipLaunchKernelGGL(k_recur12, dim3(B_DIM), dim3(1024), 0, stream,
                       x, wihT, whh4, W_ih, W_halt, b_ih, b_hh, b_halt,
                       out, psum);
    hipLaunchKernelGGL(k_y, dim3((T_DIM * B_DIM) / 16), dim3(256), 0, stream,
                       woutT, b_out, psum, out);
}